// Round 18
// baseline (186.054 us; speedup 1.0000x reference)
//
#include <hip/hip_runtime.h>
#include <hip/hip_bf16.h>
#include <math.h>

#define BB 8
#define CC 384
#define HH 14
#define WW 14
#define NHEADS 12
#define RH 7
#define RW 7
#define NN 196
#define SS 49
#define KKK 9
#define SK 58
#define TH 27
#define NTOK 1568
#define WSZ 147456
#define WO2SZ 150528

typedef float    f4 __attribute__((ext_vector_type(4)));
typedef _Float16 h8 __attribute__((ext_vector_type(8)));
typedef _Float16 h4 __attribute__((ext_vector_type(4)));

__device__ __forceinline__ float geluf(float x){ return 0.5f*x*(1.0f+erff(x*0.7071067811865475f)); }
__device__ __forceinline__ f4 mfma16h(h8 a, h8 b, f4 c){
  return __builtin_amdgcn_mfma_f32_16x16x32_f16(a, b, c, 0, 0, 0);
}

__constant__ float c_offm[9][2] = {{0,-1},{-1,-1},{-1,0},{-1,1},{0,1},{1,1},{1,0},{1,-1},{0,0}};

// ---- k_pre: (0-63) transpose x -> fp16 token-major;
//      (64-423) five 384x384 weights -> fp16; (424-497) Wo2 (392x384) -> fp16;
//      (498-532) transpose pos (12,27,27) -> pos_t (27*27,12) ----
__global__ void __launch_bounds__(256) k_pre(const float* __restrict__ x,
    _Float16* __restrict__ xhh,
    const float* __restrict__ Wq, const float* __restrict__ Wk, const float* __restrict__ Wo1,
    const float* __restrict__ Wp, const float* __restrict__ Wv, const float* __restrict__ Wo2,
    _Float16* __restrict__ Wh,
    const float* __restrict__ pos, float* __restrict__ pos_t){
  __shared__ float tile[48*203];
  int bid = blockIdx.x;
  int t = threadIdx.x;
  if (bid < 64){
    int b = bid >> 3, c0 = (bid & 7)*48;
    for (int i = t; i < 48*49; i += 256){
      int row = i / 49, seg = i % 49;
      f4 v = *(const f4*)(x + ((size_t)(b*CC + c0 + row))*NN + seg*4);
      #pragma unroll
      for (int j = 0; j < 4; ++j) tile[row*203 + seg*4 + j] = v[j];
    }
    __syncthreads();
    for (int i = t; i < 196*12; i += 256){
      int n = i / 12, seg = i % 12;
      h4 vh;
      #pragma unroll
      for (int j = 0; j < 4; ++j) vh[j] = (_Float16)tile[(seg*4 + j)*203 + n];
      *(h4*)(xhh + ((size_t)(b*NN + n))*CC + c0 + seg*4) = vh;
    }
  } else if (bid < 424){
    int bid2 = bid - 64;
    int mat = bid2 / 72;
    int e0 = (bid2 % 72)*2048 + t*8;
    const float* src = mat==0?Wq: mat==1?Wk: mat==2?Wo1: mat==3?Wp: Wv;
    f4 v0 = *(const f4*)(src + e0);
    f4 v1 = *(const f4*)(src + e0 + 4);
    h8 hi;
    #pragma unroll
    for (int j = 0; j < 4; ++j){ hi[j] = (_Float16)v0[j]; hi[4+j] = (_Float16)v1[j]; }
    *(h8*)(Wh + (size_t)mat*WSZ + e0) = hi;
  } else if (bid < 498){
    int e0 = (bid - 424)*2048 + t*8;
    if (e0 < WO2SZ){
      f4 v0 = *(const f4*)(Wo2 + e0);
      f4 v1 = *(const f4*)(Wo2 + e0 + 4);
      h8 hi;
      #pragma unroll
      for (int j = 0; j < 4; ++j){ hi[j] = (_Float16)v0[j]; hi[4+j] = (_Float16)v1[j]; }
      *(h8*)(Wh + (size_t)5*WSZ + e0) = hi;
    }
  } else {
    int p = (bid - 498)*256 + t;
    if (p < NHEADS*TH*TH){
      int h = p / (TH*TH), yx = p - h*(TH*TH);
      pos_t[yx*NHEADS + h] = pos[p];
    }
  }
}

// ---- 64x64 staged GEMM body, single fp16, K=384, global prefetch ----
__device__ __forceinline__ void gemm_fp16_body(
    const _Float16* __restrict__ Ahg, const _Float16* __restrict__ Bhg,
    int arow, int brow, _Float16* sbuf, int t, f4 acc[4]){
  _Float16* Ah = sbuf; _Float16* Bh = sbuf + 2560;
  int w = t>>6, lane = t&63, col = lane&15, quad = lane>>4;
  int r = t>>2, cg = t&3;
  const _Float16* Arh = Ahg + (size_t)arow*384 + cg*8;
  const _Float16* Brh = Bhg + (size_t)brow*384 + cg*8;
  h8 ah = *(const h8*)(Arh);
  h8 bh = *(const h8*)(Brh);
  for (int k0 = 0; k0 < 384; k0 += 32){
    __syncthreads();
    *(h8*)(Ah + r*40 + cg*8) = ah;
    *(h8*)(Bh + r*40 + cg*8) = bh;
    __syncthreads();
    if (k0 < 352){
      ah = *(const h8*)(Arh + k0 + 32);
      bh = *(const h8*)(Brh + k0 + 32);
    }
    h8 afh = *(const h8*)(Ah + (w*16+col)*40 + quad*8);
    #pragma unroll
    for (int nt = 0; nt < 4; ++nt){
      h8 bfh = *(const h8*)(Bh + (nt*16+col)*40 + quad*8);
      acc[nt] = mfma16h(afh, bfh, acc[nt]);
    }
  }
}

// ------- merged Q-proj + K-proj + VprojT -------
__global__ void __launch_bounds__(256) k_qkv(
    const _Float16* __restrict__ xhh,
    const _Float16* __restrict__ Wh,
    const float* __restrict__ bq,
    float* __restrict__ qf, _Float16* __restrict__ qfh,
    _Float16* __restrict__ K2h, _Float16* __restrict__ VprojT){
  __shared__ __align__(16) _Float16 sbuf[5120];
  int t = threadIdx.x;
  int w = t>>6, lane = t&63, col = lane&15, quad = lane>>4;
  int bid = blockIdx.x;

  if (bid < 300){
    int isK = (bid >= 150) ? 1 : 0;
    int r2 = isK ? bid - 150 : bid;
    const _Float16* Bh = Wh + (size_t)(isK ? 1 : 0)*WSZ;
    int m0 = (r2/6)*64, n0 = (r2%6)*64;
    int r = t>>2;
    int arow = min(m0 + r, NTOK-1);
    int brow = n0 + r;
    f4 acc[4] = {{0,0,0,0},{0,0,0,0},{0,0,0,0},{0,0,0,0}};
    gemm_fp16_body(xhh, Bh, arow, brow, sbuf, t, acc);
    #pragma unroll
    for (int nt = 0; nt < 4; ++nt){
      #pragma unroll
      for (int rr = 0; rr < 4; ++rr){
        int m = m0 + w*16 + quad*4 + rr;
        int o = n0 + nt*16 + col;
        if (m >= NTOK) continue;
        if (isK){
          K2h[(size_t)m*384 + o] = (_Float16)acc[nt][rr];
        } else {
          float v = acc[nt][rr] + bq[o];
          qf[(size_t)m*384 + o] = v;
          qfh[(size_t)m*384 + o] = (_Float16)v;
        }
      }
    }
  } else {
    // VprojT: direct-fragment GEMM, A = Wv fp16 (slot 4), B = xhh
    int idx = bid - 300;
    int mo = idx % 6;
    int ny = (idx / 6) % 4;
    int b  = idx / 24;
    int m0 = mo*64, n0 = ny*64;
    int orow = m0 + w*16 + col;
    const _Float16* wvh = Wh + (size_t)4*WSZ + (size_t)orow*384;
    f4 acc[4] = {{0,0,0,0},{0,0,0,0},{0,0,0,0},{0,0,0,0}};
    for (int kt = 0; kt < 12; ++kt){
      h8 ah = *(const h8*)(wvh + kt*32 + quad*8);
      #pragma unroll
      for (int nt = 0; nt < 4; ++nt){
        int i = min(n0 + nt*16 + col, 195);
        h8 b8 = *(const h8*)(xhh + ((size_t)(b*196 + i))*384 + kt*32 + quad*8);
        acc[nt] = mfma16h(ah, b8, acc[nt]);
      }
    }
    #pragma unroll
    for (int nt = 0; nt < 4; ++nt){
      #pragma unroll
      for (int rr = 0; rr < 4; ++rr){
        int o = m0 + w*16 + quad*4 + rr;
        int i = n0 + nt*16 + col;
        if (i < 224)
          VprojT[((size_t)(b*384 + o))*224 + i] = (i < 196) ? (_Float16)acc[nt][rr] : (_Float16)0.f;
      }
    }
  }
}

// ---- merged: Wo1-GELU GEMM (150 blocks) + G-GEMM (384 blocks) -------
__global__ void __launch_bounds__(256) k_mid(
    const _Float16* __restrict__ qfh,
    const _Float16* __restrict__ Wh,
    const float* __restrict__ bo1, float* __restrict__ t1,
    const _Float16* __restrict__ K2h, _Float16* __restrict__ G16){
  __shared__ __align__(16) _Float16 sbuf[5120];
  int t = threadIdx.x;
  int w = t>>6, lane = t&63, col = lane&15, quad = lane>>4;
  int bid = blockIdx.x;
  if (bid < 150){
    const _Float16* Bh = Wh + (size_t)2*WSZ;   // Wo1
    int m0 = (bid/6)*64, n0 = (bid%6)*64;
    int r = t>>2;
    int arow = min(m0 + r, NTOK-1);
    int brow = n0 + r;
    f4 acc[4] = {{0,0,0,0},{0,0,0,0},{0,0,0,0},{0,0,0,0}};
    gemm_fp16_body(qfh, Bh, arow, brow, sbuf, t, acc);
    #pragma unroll
    for (int nt = 0; nt < 4; ++nt){
      #pragma unroll
      for (int rr = 0; rr < 4; ++rr){
        int m = m0 + w*16 + quad*4 + rr;
        int o = n0 + nt*16 + col;
        if (m >= NTOK) continue;
        t1[(size_t)m*384 + o] = geluf(acc[nt][rr] + bo1[o]);
      }
    }
  } else {
    int idx = bid - 150;
    int m0 = (idx & 3)*64;
    int bh = idx >> 2; int b = bh / 12, h = bh - b*12;
    const _Float16* qr = qfh + ((size_t)(b*196 + min(m0 + w*16 + col, 195)))*384 + h*32;
    h8 a8 = *(const h8*)(qr + quad*8);
    f4 acc[13];
    #pragma unroll
    for (int nt = 0; nt < 13; ++nt){
      int i = min(nt*16 + col, 195);
      h8 b8 = *(const h8*)(K2h + ((size_t)(b*196 + i))*384 + h*32 + quad*8);
      f4 z = {0.f,0.f,0.f,0.f};
      acc[nt] = mfma16h(a8, b8, z);
    }
    #pragma unroll
    for (int nt = 0; nt < 13; ++nt){
      #pragma unroll
      for (int r = 0; r < 4; ++r){
        int m = m0 + w*16 + quad*4 + r;
        int i = nt*16 + col;
        if (m < 196 && i < 196)
          G16[((size_t)(b*196 + m))*2352 + h*196 + i] = (_Float16)acc[nt][r];
      }
    }
  }
}

// ---------------- depthwise 3x3 s2 conv + LN + GELU -> fp16 ----------
__global__ void __launch_bounds__(384) k_dwln(const float* __restrict__ t1,
      const float* __restrict__ Wdw, const float* __restrict__ bdw,
      const float* __restrict__ lng, const float* __restrict__ lnb,
      _Float16* __restrict__ t2h){
  int blk = blockIdx.x;
  int ow = blk % RW; int oh = (blk / RW) % RH; int b = blk / (RH*RW);
  int c = threadIdx.x;
  float acc = bdw[c];
  #pragma unroll
  for (int kh = 0; kh < 3; ++kh){
    int ih = oh*2 - 1 + kh;
    if (ih < 0 || ih >= HH) continue;
    #pragma unroll
    for (int kw = 0; kw < 3; ++kw){
      int iw = ow*2 - 1 + kw;
      if (iw < 0 || iw >= WW) continue;
      acc += t1[((b*HH + ih)*WW + iw)*CC + c] * Wdw[c*9 + kh*3 + kw];
    }
  }
  __shared__ float red[6];
  __shared__ float s_mu, s_rv;
  float v = acc;
  #pragma unroll
  for (int o = 32; o > 0; o >>= 1) v += __shfl_down(v, o);
  int wid = c >> 6, lane = c & 63;
  if (lane == 0) red[wid] = v;
  __syncthreads();
  if (c == 0){ float s = 0.f; for (int i = 0; i < 6; ++i) s += red[i]; s_mu = s / CC; }
  __syncthreads();
  float mu = s_mu;
  float d = acc - mu;
  v = d*d;
  #pragma unroll
  for (int o = 32; o > 0; o >>= 1) v += __shfl_down(v, o);
  if (lane == 0) red[wid] = v;
  __syncthreads();
  if (c == 0){ float s = 0.f; for (int i = 0; i < 6; ++i) s += red[i]; s_rv = rsqrtf(s / CC + 1e-5f); }
  __syncthreads();
  float val = geluf(d * s_rv * lng[c] + lnb[c]);
  t2h[blk*CC + c] = (_Float16)val;
}

// ------------- offset head GEMM (49 blocks) -> offp -------------
__global__ void __launch_bounds__(256) k_off(
    const _Float16* __restrict__ t2h,
    const _Float16* __restrict__ Wh,
    float* __restrict__ offp){
  __shared__ __align__(16) _Float16 sbuf[5120];
  int t = threadIdx.x;
  int w = t>>6, lane = t&63, col = lane&15, quad = lane>>4;
  int bid = blockIdx.x;
  int m0 = (bid/7)*64, n0 = (bid%7)*64;
  int r = t>>2;
  int arow = min(m0 + r, 391);
  int brow = min(n0 + r, 391);
  const _Float16* Bh = Wh + (size_t)5*WSZ;   // Wo2 (392x384)
  f4 acc[4] = {{0,0,0,0},{0,0,0,0},{0,0,0,0},{0,0,0,0}};
  gemm_fp16_body(t2h, Bh, arow, brow, sbuf, t, acc);
  #pragma unroll
  for (int nt = 0; nt < 4; ++nt){
    #pragma unroll
    for (int rr = 0; rr < 4; ++rr){
      int row = m0 + w*16 + quad*4 + rr;
      int o = n0 + nt*16 + col;
      if (row < 392 && o < 392){
        int g = o / NN, nn = o % NN;
        int b = row / SS, s = row % SS;
        float rng = (g == 0) ? (1.0f/HH) : (1.0f/WW);
        offp[((b*NN + nn)*SS + s)*2 + g] = tanhf(acc[nt][rr]) * rng * 2.0f;
      }
    }
  }
}

// ---------------- fused per-token: taps + softmax + agg scatter (no MFMA) ---
// pos_t is the (27*27, 12) head-minor transpose: the 4 threads of an s-group
// read one contiguous 48B segment per corner (coalesced) instead of 12
// scattered head-major lines.
__global__ void __launch_bounds__(256, 4) k_fused(
    const float* __restrict__ qf, const float* __restrict__ off,
    const _Float16* __restrict__ G16,
    const float* __restrict__ bk, const float* __restrict__ Wco, const float* __restrict__ pos_t,
    _Float16* __restrict__ agg16){
  __shared__ __align__(16) _Float16 Gs[2352];
  __shared__ __align__(16) float agg[12*228];    // front 384 aliases qrow
  __shared__ float scoreS[696];                  // [h*58+s]
  __shared__ float offl[98];
  __shared__ float colb[18];
  __shared__ float qbv[12];
  __shared__ uint2 tapv[232];                    // .x = weight f32 bits, .y = cell idx
  float* qrow = agg;

  int blk = blockIdx.x;
  int n = blk % NN, b = blk / NN;
  int iy = n / WW, ix = n % WW;
  int t = threadIdx.x;

  // ---- P0: vectorized loads ----
  {
    const h8* g8 = (const h8*)(G16 + (size_t)blk*2352);
    h8* gs8 = (h8*)Gs;
    for (int i = t; i < 294; i += 256) gs8[i] = g8[i];
  }
  {
    const f4* q4 = (const f4*)(qf + (size_t)blk*384);
    f4* qr4 = (f4*)qrow;
    for (int i = t; i < 96; i += 256) qr4[i] = q4[i];
  }
  for (int i = t; i < 98; i += 256) offl[i] = off[(size_t)blk*98 + i];
  __syncthreads();

  // ---- P1a: colb (co) and qbv[h] = q_h·bk_h ----
  if (t < 144){
    int o = t >> 3, l = t & 7;
    const float* wr = Wco + o*384 + l*48;
    const float* qr = qrow + l*48;
    f4 a4 = {0.f,0.f,0.f,0.f};
    #pragma unroll
    for (int c = 0; c < 48; c += 4) a4 += (*(const f4*)(qr + c)) * (*(const f4*)(wr + c));
    float acc = a4[0]+a4[1]+a4[2]+a4[3];
    acc += __shfl_xor(acc, 1); acc += __shfl_xor(acc, 2); acc += __shfl_xor(acc, 4);
    if (l == 0){
      int g = o & 1;
      float range = (g == 0) ? (1.0f/HH) : (1.0f/WW);
      colb[o] = tanhf(acc) * range;
    }
  }
  if (t >= 160){
    int o = t - 160;
    int h = o >> 3, l = o & 7;
    float acc = 0.f;
    for (int d = l; d < 32; d += 8) acc += qrow[h*32 + d] * bk[h*32 + d];
    acc += __shfl_xor(acc, 1); acc += __shfl_xor(acc, 2); acc += __shfl_xor(acc, 4);
    if (l == 0 && h < 12) qbv[h] = acc;
  }
  __syncthreads();

  // ---- P1b: taps (t<58) ----
  if (t < SK){
    float cy, cx;
    if (t < SS){
      int sy = t / RW, sx = t % RW;
      cy = offl[t*2+0] + ((2.0f*sy)/13.0f*2.0f - 1.0f);
      cx = offl[t*2+1] + ((2.0f*sx)/13.0f*2.0f - 1.0f);
    } else {
      int kk = t - SS;
      float cyr = fminf(fmaxf((float)iy + c_offm[kk][0], 0.f), (float)HH);
      float cxr = fminf(fmaxf((float)ix + c_offm[kk][1], 0.f), (float)WW);
      cy = colb[kk*2+0] + (cyr/13.0f*2.0f - 1.0f);
      cx = colb[kk*2+1] + (cxr/13.0f*2.0f - 1.0f);
    }
    float py = (cy + 1.0f)*0.5f*13.0f;
    float px = (cx + 1.0f)*0.5f*13.0f;
    float y0 = floorf(py), x0 = floorf(px);
    float wy1 = py - y0, wx1 = px - x0;
    #pragma unroll
    for (int k4 = 0; k4 < 4; ++k4){
      float yf = y0 + (k4 >> 1), xf = x0 + (k4 & 1);
      bool valid = (yf >= 0.f) && (yf <= 13.f) && (xf >= 0.f) && (xf <= 13.f);
      int yi = (int)fminf(fmaxf(yf, 0.f), 13.f);
      int xi = (int)fminf(fmaxf(xf, 0.f), 13.f);
      float wgt = ((k4 >> 1) ? wy1 : (1.f - wy1)) * ((k4 & 1) ? wx1 : (1.f - wx1));
      tapv[t*4 + k4] = make_uint2(__float_as_uint(valid ? wgt : 0.f),
                                  (unsigned)(yi*WW + xi));
    }
  }
  __syncthreads();   // taps + colb ready; now zero agg (qrow dead)
  for (int i = t; i < 12*228; i += 256) agg[i] = 0.f;

  // ---- P2 (s-major): 58 s x 4 groups of 3 heads; pos_t coalesced gather ----
  if (t < 232){
    int s = t >> 2, grp = t & 3;
    float ry, rx;
    if (s < SS){
      int sy = s / RW, sx = s % RW;
      ry = (2.0f*sy - iy)/13.0f - offl[s*2+0];
      rx = (2.0f*sx - ix)/13.0f - offl[s*2+1];
    } else {
      int kk = s - SS;
      ry = colb[kk*2+0] - (float)iy;
      rx = colb[kk*2+1] - (float)ix;
    }
    float py = (ry + 1.0f)*0.5f*26.0f;
    float px = (rx + 1.0f)*0.5f*26.0f;
    float y0 = floorf(py), x0 = floorf(px);
    float wy1 = py - y0, wx1 = px - x0;
    int pidx[4]; float pw[4];
    #pragma unroll
    for (int k4 = 0; k4 < 4; ++k4){
      float yf = y0 + (k4 >> 1), xf = x0 + (k4 & 1);
      bool valid = (yf >= 0.f) && (yf <= 26.f) && (xf >= 0.f) && (xf <= 26.f);
      int yi = (int)fminf(fmaxf(yf, 0.f), 26.f);
      int xi = (int)fminf(fmaxf(xf, 0.f), 26.f);
      pidx[k4] = yi*TH + xi;
      float wgt = ((k4 >> 1) ? wy1 : (1.f - wy1)) * ((k4 & 1) ? wx1 : (1.f - wx1));
      pw[k4] = valid ? wgt : 0.f;
    }
    uint2 tp0 = tapv[s*4+0], tp1 = tapv[s*4+1], tp2 = tapv[s*4+2], tp3 = tapv[s*4+3];
    float tw0 = __uint_as_float(tp0.x), tw1 = __uint_as_float(tp1.x);
    float tw2 = __uint_as_float(tp2.x), tw3 = __uint_as_float(tp3.x);
    // coalesced: heads for one corner are contiguous in pos_t
    float pv[3][4], gv[3][4];
    #pragma unroll
    for (int k4 = 0; k4 < 4; ++k4){
      const float* pp = pos_t + pidx[k4]*NHEADS + grp*3;
      pv[0][k4] = pp[0]; pv[1][k4] = pp[1]; pv[2][k4] = pp[2];
    }
    #pragma unroll
    for (int hh = 0; hh < 3; ++hh){
      const _Float16* gh = Gs + (grp*3 + hh)*196;
      gv[hh][0] = (float)gh[(int)tp0.y]; gv[hh][1] = (float)gh[(int)tp1.y];
      gv[hh][2] = (float)gh[(int)tp2.y]; gv[hh][3] = (float)gh[(int)tp3.y];
    }
    #pragma unroll
    for (int hh = 0; hh < 3; ++hh){
      int h = grp*3 + hh;
      float val = qbv[h];
      val += pv[hh][0]*pw[0];
      val += pv[hh][1]*pw[1];
      val += pv[hh][2]*pw[2];
      val += pv[hh][3]*pw[3];
      val += tw0*gv[hh][0];
      val += tw1*gv[hh][1];
      val += tw2*gv[hh][2];
      val += tw3*gv[hh][3];
      scoreS[h*58 + s] = val;
    }
  }
  __syncthreads();

  // ---- P3: softmax per head (192 threads) ----
  if (t < 192){
    int h = t >> 4, l = t & 15;
    float v[4];
    #pragma unroll
    for (int k = 0; k < 4; ++k){ int s = l + 16*k; v[k] = (s < SK) ? scoreS[h*58 + s] : -1e30f; }
    float mx = fmaxf(fmaxf(v[0], v[1]), fmaxf(v[2], v[3]));
    mx = fmaxf(mx, __shfl_xor(mx, 1)); mx = fmaxf(mx, __shfl_xor(mx, 2));
    mx = fmaxf(mx, __shfl_xor(mx, 4)); mx = fmaxf(mx, __shfl_xor(mx, 8));
    float e[4], sum = 0.f;
    #pragma unroll
    for (int k = 0; k < 4; ++k){ int s = l + 16*k; e[k] = (s < SK) ? expf(v[k] - mx) : 0.f; sum += e[k]; }
    sum += __shfl_xor(sum, 1); sum += __shfl_xor(sum, 2);
    sum += __shfl_xor(sum, 4); sum += __shfl_xor(sum, 8);
    float inv = 1.0f / sum;
    #pragma unroll
    for (int k = 0; k < 4; ++k){
      int s = l + 16*k;
      if (s < SK) scoreS[h*58 + s] = e[k]*inv;
    }
  }
  __syncthreads();

  // ---- P4 (tap-major): 232 threads, each scatters its tap into all 12 heads --
  if (t < 232){
    uint2 tp = tapv[t];
    float wv = __uint_as_float(tp.x);
    if (wv != 0.f){
      int s = t >> 2, cell = (int)tp.y;
      float* ag = agg + cell;
      #pragma unroll
      for (int h = 0; h < 12; ++h)
        atomicAdd(ag + h*228, scoreS[h*58 + s]*wv);
    }
  }
  __syncthreads();

  // ---- P5: vectorized write agg16 (dense 224-stride; pads are zero) ----
  {
    _Float16* ar = agg16 + (size_t)blk*2688;
    for (int i = t; i < 336; i += 256){
      int d = i*8;
      int h = d / 224, j = d - h*224;
      const float* src = agg + h*228 + j;
      f4 a = *(const f4*)src;
      f4 c = *(const f4*)(src + 4);
      h8 o;
      #pragma unroll
      for (int k = 0; k < 4; ++k){ o[k] = (_Float16)a[k]; o[4+k] = (_Float16)c[k]; }
      *(h8*)(ar + d) = o;
    }
  }
}

// -------- AV-GEMM -> otok fp16 --------
__global__ void __launch_bounds__(256) k_av(const _Float16* __restrict__ agg16,
                                            const _Float16* __restrict__ VprojT,
                                            const float* __restrict__ bv,
                                            _Float16* __restrict__ otokh){
  int t = threadIdx.x;
  int w = t>>6, lane = t&63, col = lane&15, quad = lane>>4;
  int m0 = blockIdx.x*64;
  int bh = blockIdx.y; int b = bh / 12, h = bh - b*12;
  const _Float16* ar = agg16 + ((size_t)(b*196 + min(m0 + w*16 + col, 195)))*2688 + h*224;
  f4 acc[2] = {{0,0,0,0},{0,0,0,0}};
  for (int kt = 0; kt < 7; ++kt){
    h8 a8 = *(const h8*)(ar + kt*32 + quad*8);
    #pragma unroll
    for (int nt = 0; nt < 2; ++nt){
      int o = h*32 + nt*16 + col;
      h8 b8 = *(const h8*)(VprojT + ((size_t)(b*384 + o))*224 + kt*32 + quad*8);
      acc[nt] = mfma16h(a8, b8, acc[nt]);
    }
  }
  #pragma unroll
  for (int nt = 0; nt < 2; ++nt){
    #pragma unroll
    for (int rr = 0; rr < 4; ++rr){
      int m = m0 + w*16 + quad*4 + rr;
      if (m < 196){
        int o = h*32 + nt*16 + col;
        float v = acc[nt][rr] + bv[o];
        otokh[((size_t)(b*196 + m))*384 + o] = (_Float16)v;
      }
    }
  }
}

// -------- final projection GEMM (fp16), transpose-scatter epilogue -----
__global__ void __launch_bounds__(256) k_proj(
    const _Float16* __restrict__ otokh,
    const _Float16* __restrict__ Wh,
    const float* __restrict__ bias, float* __restrict__ out){
  __shared__ __align__(16) _Float16 sbuf[5120];
  __shared__ float tile[16*65];
  int t = threadIdx.x;
  int w = t>>6, lane = t&63, col = lane&15, quad = lane>>4;
  int m0 = blockIdx.x*64, n0 = blockIdx.y*64;
  int r = t>>2;
  int arow = min(m0 + r, NTOK-1);
  int brow = n0 + r;
  const _Float16* Bh = Wh + (size_t)3*WSZ;   // Wp
  f4 acc[4] = {{0,0,0,0},{0,0,0,0},{0,0,0,0},{0,0,0,0}};
  gemm_fp16_body(otokh, Bh, arow, brow, sbuf, t, acc);
  // transpose-scatter in 4 passes of 16 m-rows through a 16x65 f32 tile
  #pragma unroll
  for (int pass = 0; pass < 4; ++pass){
    __syncthreads();
    if (w == pass){
      #pragma unroll
      for (int nt = 0; nt < 4; ++nt)
        #pragma unroll
        for (int rr = 0; rr < 4; ++rr)
          tile[(quad*4 + rr)*65 + nt*16 + col] = acc[nt][rr];
    }
    __syncthreads();
    for (int i = t; i < 256; i += 256){
      int o_l = i >> 2, ms = i & 3;
      int m = m0 + pass*16 + ms*4;
      if (m >= NTOK) continue;
      int bb = m / NN, nnn = m % NN;
      int o = n0 + o_l;
      float bo = bias[o];
      f4 v = { tile[(ms*4+0)*65 + o_l] + bo, tile[(ms*4+1)*65 + o_l] + bo,
               tile[(ms*4+2)*65 + o_l] + bo, tile[(ms*4+3)*65 + o_l] + bo };
      *(f4*)(out + ((size_t)bb*384 + o)*NN + nnn) = v;
    }
  }
}

extern "C" void kernel_launch(void* const* d_in, const int* in_sizes, int n_in,
                              void* d_out, int out_size, void* d_ws, size_t ws_size,
                              hipStream_t stream){
  const float* x    = (const float*)d_in[0];
  const float* Wq   = (const float*)d_in[1];
  const float* bq   = (const float*)d_in[2];
  const float* Wk   = (const float*)d_in[3];
  const float* bk   = (const float*)d_in[4];
  const float* Wv   = (const float*)d_in[5];
  const float* bv   = (const float*)d_in[6];
  const float* Wo1  = (const float*)d_in[7];
  const float* bo1  = (const float*)d_in[8];
  const float* Wdw  = (const float*)d_in[9];
  const float* bdw  = (const float*)d_in[10];
  const float* ln_g = (const float*)d_in[11];
  const float* ln_b = (const float*)d_in[12];
  const float* Wo2  = (const float*)d_in[13];
  const float* Wco  = (const float*)d_in[14];
  const float* pos  = (const float*)d_in[15];
  const float* Wp   = (const float*)d_in[16];
  const float* bp   = (const float*)d_in[17];
  float* out = (float*)d_out;

  float* ws   = (float*)d_ws;
  float* qf   = ws;                    // 602112 f32
  float* t1   = qf   + 602112;         // 602112 f32
  float* offp = t1   + 602112;         // 153664 f32
  float* pos_t = offp + 153664;        // 8748 f32
  _Float16* xhh    = (_Float16*)(pos_t + 8748);    // 602112 h
  _Float16* qfh    = xhh    + 602112;              // 602112 h
  _Float16* t2h    = qfh    + 602112;              // 150528 h
  _Float16* K2h    = t2h    + 150528;              // 602112 h
  _Float16* VprojT = K2h    + 602112;              // 688128 h
  _Float16* otokh  = VprojT + 688128;              // 602112 h
  _Float16* Wh     = otokh  + 602112;              // 5*147456 + 150528 h
  _Float16* G16    = Wh     + 5*WSZ + WO2SZ;       // 1568*2352 h
  _Float16* agg16  = G16    + 3687936;             // 1568*2688 h

  k_pre<<<533, 256, 0, stream>>>(x, xhh, Wq, Wk, Wo1, Wp, Wv, Wo2, Wh, pos, pos_t);
  k_qkv<<<492, 256, 0, stream>>>(xhh, Wh, bq, qf, qfh, K2h, VprojT);
  k_mid<<<534, 256, 0, stream>>>(qfh, Wh, bo1, t1, K2h, G16);
  k_dwln<<<392, 384, 0, stream>>>(t1, Wdw, bdw, ln_g, ln_b, t2h);
  k_off<<<49, 256, 0, stream>>>(t2h, Wh, offp);
  k_fused<<<1568, 256, 0, stream>>>(qf, offp, G16, bk, Wco, pos_t, agg16);
  k_av<<<dim3(4,96), 256, 0, stream>>>(agg16, VprojT, bv, otokh);
  k_proj<<<dim3(25,6), 256, 0, stream>>>(otokh, Wh, bp, out);
}

// Round 19
// 180.920 us; speedup vs baseline: 1.0284x; 1.0284x over previous
//
#include <hip/hip_runtime.h>
#include <hip/hip_bf16.h>
#include <math.h>

#define BB 8
#define CC 384
#define HH 14
#define WW 14
#define NHEADS 12
#define RH 7
#define RW 7
#define NN 196
#define SS 49
#define KKK 9
#define SK 58
#define TH 27
#define NTOK 1568
#define WSZ 147456
#define WO2SZ 150528

typedef float    f4 __attribute__((ext_vector_type(4)));
typedef _Float16 h8 __attribute__((ext_vector_type(8)));
typedef _Float16 h4 __attribute__((ext_vector_type(4)));

__device__ __forceinline__ float geluf(float x){ return 0.5f*x*(1.0f+erff(x*0.7071067811865475f)); }
__device__ __forceinline__ f4 mfma16h(h8 a, h8 b, f4 c){
  return __builtin_amdgcn_mfma_f32_16x16x32_f16(a, b, c, 0, 0, 0);
}

__constant__ float c_offm[9][2] = {{0,-1},{-1,-1},{-1,0},{-1,1},{0,1},{1,1},{1,0},{1,-1},{0,0}};

// ---- k_pre: (0-63) transpose x -> fp16 token-major;
//      (64-423) five 384x384 weights -> fp16; (424-497) Wo2 (392x384) -> fp16 ----
__global__ void __launch_bounds__(256) k_pre(const float* __restrict__ x,
    _Float16* __restrict__ xhh,
    const float* __restrict__ Wq, const float* __restrict__ Wk, const float* __restrict__ Wo1,
    const float* __restrict__ Wp, const float* __restrict__ Wv, const float* __restrict__ Wo2,
    _Float16* __restrict__ Wh){
  __shared__ float tile[48*203];
  int bid = blockIdx.x;
  int t = threadIdx.x;
  if (bid < 64){
    int b = bid >> 3, c0 = (bid & 7)*48;
    for (int i = t; i < 48*49; i += 256){
      int row = i / 49, seg = i % 49;
      f4 v = *(const f4*)(x + ((size_t)(b*CC + c0 + row))*NN + seg*4);
      #pragma unroll
      for (int j = 0; j < 4; ++j) tile[row*203 + seg*4 + j] = v[j];
    }
    __syncthreads();
    for (int i = t; i < 196*12; i += 256){
      int n = i / 12, seg = i % 12;
      h4 vh;
      #pragma unroll
      for (int j = 0; j < 4; ++j) vh[j] = (_Float16)tile[(seg*4 + j)*203 + n];
      *(h4*)(xhh + ((size_t)(b*NN + n))*CC + c0 + seg*4) = vh;
    }
  } else if (bid < 424){
    int bid2 = bid - 64;
    int mat = bid2 / 72;
    int e0 = (bid2 % 72)*2048 + t*8;
    const float* src = mat==0?Wq: mat==1?Wk: mat==2?Wo1: mat==3?Wp: Wv;
    f4 v0 = *(const f4*)(src + e0);
    f4 v1 = *(const f4*)(src + e0 + 4);
    h8 hi;
    #pragma unroll
    for (int j = 0; j < 4; ++j){ hi[j] = (_Float16)v0[j]; hi[4+j] = (_Float16)v1[j]; }
    *(h8*)(Wh + (size_t)mat*WSZ + e0) = hi;
  } else {
    int e0 = (bid - 424)*2048 + t*8;
    if (e0 < WO2SZ){
      f4 v0 = *(const f4*)(Wo2 + e0);
      f4 v1 = *(const f4*)(Wo2 + e0 + 4);
      h8 hi;
      #pragma unroll
      for (int j = 0; j < 4; ++j){ hi[j] = (_Float16)v0[j]; hi[4+j] = (_Float16)v1[j]; }
      *(h8*)(Wh + (size_t)5*WSZ + e0) = hi;
    }
  }
}

// ---- 64x64 staged GEMM body, single fp16, K=384, global prefetch ----
__device__ __forceinline__ void gemm_fp16_body(
    const _Float16* __restrict__ Ahg, const _Float16* __restrict__ Bhg,
    int arow, int brow, _Float16* sbuf, int t, f4 acc[4]){
  _Float16* Ah = sbuf; _Float16* Bh = sbuf + 2560;
  int w = t>>6, lane = t&63, col = lane&15, quad = lane>>4;
  int r = t>>2, cg = t&3;
  const _Float16* Arh = Ahg + (size_t)arow*384 + cg*8;
  const _Float16* Brh = Bhg + (size_t)brow*384 + cg*8;
  h8 ah = *(const h8*)(Arh);
  h8 bh = *(const h8*)(Brh);
  for (int k0 = 0; k0 < 384; k0 += 32){
    __syncthreads();
    *(h8*)(Ah + r*40 + cg*8) = ah;
    *(h8*)(Bh + r*40 + cg*8) = bh;
    __syncthreads();
    if (k0 < 352){
      ah = *(const h8*)(Arh + k0 + 32);
      bh = *(const h8*)(Brh + k0 + 32);
    }
    h8 afh = *(const h8*)(Ah + (w*16+col)*40 + quad*8);
    #pragma unroll
    for (int nt = 0; nt < 4; ++nt){
      h8 bfh = *(const h8*)(Bh + (nt*16+col)*40 + quad*8);
      acc[nt] = mfma16h(afh, bfh, acc[nt]);
    }
  }
}

// ------- merged Q-proj + K-proj + VprojT -------
__global__ void __launch_bounds__(256) k_qkv(
    const _Float16* __restrict__ xhh,
    const _Float16* __restrict__ Wh,
    const float* __restrict__ bq,
    float* __restrict__ qf, _Float16* __restrict__ qfh,
    _Float16* __restrict__ K2h, _Float16* __restrict__ VprojT){
  __shared__ __align__(16) _Float16 sbuf[5120];
  int t = threadIdx.x;
  int w = t>>6, lane = t&63, col = lane&15, quad = lane>>4;
  int bid = blockIdx.x;

  if (bid < 300){
    int isK = (bid >= 150) ? 1 : 0;
    int r2 = isK ? bid - 150 : bid;
    const _Float16* Bh = Wh + (size_t)(isK ? 1 : 0)*WSZ;
    int m0 = (r2/6)*64, n0 = (r2%6)*64;
    int r = t>>2;
    int arow = min(m0 + r, NTOK-1);
    int brow = n0 + r;
    f4 acc[4] = {{0,0,0,0},{0,0,0,0},{0,0,0,0},{0,0,0,0}};
    gemm_fp16_body(xhh, Bh, arow, brow, sbuf, t, acc);
    #pragma unroll
    for (int nt = 0; nt < 4; ++nt){
      #pragma unroll
      for (int rr = 0; rr < 4; ++rr){
        int m = m0 + w*16 + quad*4 + rr;
        int o = n0 + nt*16 + col;
        if (m >= NTOK) continue;
        if (isK){
          K2h[(size_t)m*384 + o] = (_Float16)acc[nt][rr];
        } else {
          float v = acc[nt][rr] + bq[o];
          qf[(size_t)m*384 + o] = v;
          qfh[(size_t)m*384 + o] = (_Float16)v;
        }
      }
    }
  } else {
    // VprojT: direct-fragment GEMM, A = Wv fp16 (slot 4), B = xhh
    int idx = bid - 300;
    int mo = idx % 6;
    int ny = (idx / 6) % 4;
    int b  = idx / 24;
    int m0 = mo*64, n0 = ny*64;
    int orow = m0 + w*16 + col;
    const _Float16* wvh = Wh + (size_t)4*WSZ + (size_t)orow*384;
    f4 acc[4] = {{0,0,0,0},{0,0,0,0},{0,0,0,0},{0,0,0,0}};
    for (int kt = 0; kt < 12; ++kt){
      h8 ah = *(const h8*)(wvh + kt*32 + quad*8);
      #pragma unroll
      for (int nt = 0; nt < 4; ++nt){
        int i = min(n0 + nt*16 + col, 195);
        h8 b8 = *(const h8*)(xhh + ((size_t)(b*196 + i))*384 + kt*32 + quad*8);
        acc[nt] = mfma16h(ah, b8, acc[nt]);
      }
    }
    #pragma unroll
    for (int nt = 0; nt < 4; ++nt){
      #pragma unroll
      for (int rr = 0; rr < 4; ++rr){
        int o = m0 + w*16 + quad*4 + rr;
        int i = n0 + nt*16 + col;
        if (i < 224)
          VprojT[((size_t)(b*384 + o))*224 + i] = (i < 196) ? (_Float16)acc[nt][rr] : (_Float16)0.f;
      }
    }
  }
}

// ---- merged: Wo1-GELU GEMM (150 blocks) + G-GEMM (384 blocks) -------
__global__ void __launch_bounds__(256) k_mid(
    const _Float16* __restrict__ qfh,
    const _Float16* __restrict__ Wh,
    const float* __restrict__ bo1, float* __restrict__ t1,
    const _Float16* __restrict__ K2h, _Float16* __restrict__ G16){
  __shared__ __align__(16) _Float16 sbuf[5120];
  int t = threadIdx.x;
  int w = t>>6, lane = t&63, col = lane&15, quad = lane>>4;
  int bid = blockIdx.x;
  if (bid < 150){
    const _Float16* Bh = Wh + (size_t)2*WSZ;   // Wo1
    int m0 = (bid/6)*64, n0 = (bid%6)*64;
    int r = t>>2;
    int arow = min(m0 + r, NTOK-1);
    int brow = n0 + r;
    f4 acc[4] = {{0,0,0,0},{0,0,0,0},{0,0,0,0},{0,0,0,0}};
    gemm_fp16_body(qfh, Bh, arow, brow, sbuf, t, acc);
    #pragma unroll
    for (int nt = 0; nt < 4; ++nt){
      #pragma unroll
      for (int rr = 0; rr < 4; ++rr){
        int m = m0 + w*16 + quad*4 + rr;
        int o = n0 + nt*16 + col;
        if (m >= NTOK) continue;
        t1[(size_t)m*384 + o] = geluf(acc[nt][rr] + bo1[o]);
      }
    }
  } else {
    int idx = bid - 150;
    int m0 = (idx & 3)*64;
    int bh = idx >> 2; int b = bh / 12, h = bh - b*12;
    const _Float16* qr = qfh + ((size_t)(b*196 + min(m0 + w*16 + col, 195)))*384 + h*32;
    h8 a8 = *(const h8*)(qr + quad*8);
    f4 acc[13];
    #pragma unroll
    for (int nt = 0; nt < 13; ++nt){
      int i = min(nt*16 + col, 195);
      h8 b8 = *(const h8*)(K2h + ((size_t)(b*196 + i))*384 + h*32 + quad*8);
      f4 z = {0.f,0.f,0.f,0.f};
      acc[nt] = mfma16h(a8, b8, z);
    }
    #pragma unroll
    for (int nt = 0; nt < 13; ++nt){
      #pragma unroll
      for (int r = 0; r < 4; ++r){
        int m = m0 + w*16 + quad*4 + r;
        int i = nt*16 + col;
        if (m < 196 && i < 196)
          G16[((size_t)(b*196 + m))*2352 + h*196 + i] = (_Float16)acc[nt][r];
      }
    }
  }
}

// ---------------- depthwise 3x3 s2 conv + LN + GELU -> fp16 ----------
__global__ void __launch_bounds__(384) k_dwln(const float* __restrict__ t1,
      const float* __restrict__ Wdw, const float* __restrict__ bdw,
      const float* __restrict__ lng, const float* __restrict__ lnb,
      _Float16* __restrict__ t2h){
  int blk = blockIdx.x;
  int ow = blk % RW; int oh = (blk / RW) % RH; int b = blk / (RH*RW);
  int c = threadIdx.x;
  float acc = bdw[c];
  #pragma unroll
  for (int kh = 0; kh < 3; ++kh){
    int ih = oh*2 - 1 + kh;
    if (ih < 0 || ih >= HH) continue;
    #pragma unroll
    for (int kw = 0; kw < 3; ++kw){
      int iw = ow*2 - 1 + kw;
      if (iw < 0 || iw >= WW) continue;
      acc += t1[((b*HH + ih)*WW + iw)*CC + c] * Wdw[c*9 + kh*3 + kw];
    }
  }
  __shared__ float red[6];
  __shared__ float s_mu, s_rv;
  float v = acc;
  #pragma unroll
  for (int o = 32; o > 0; o >>= 1) v += __shfl_down(v, o);
  int wid = c >> 6, lane = c & 63;
  if (lane == 0) red[wid] = v;
  __syncthreads();
  if (c == 0){ float s = 0.f; for (int i = 0; i < 6; ++i) s += red[i]; s_mu = s / CC; }
  __syncthreads();
  float mu = s_mu;
  float d = acc - mu;
  v = d*d;
  #pragma unroll
  for (int o = 32; o > 0; o >>= 1) v += __shfl_down(v, o);
  if (lane == 0) red[wid] = v;
  __syncthreads();
  if (c == 0){ float s = 0.f; for (int i = 0; i < 6; ++i) s += red[i]; s_rv = rsqrtf(s / CC + 1e-5f); }
  __syncthreads();
  float val = geluf(d * s_rv * lng[c] + lnb[c]);
  t2h[blk*CC + c] = (_Float16)val;
}

// ------------- offset head GEMM (49 blocks) -> offp -------------
__global__ void __launch_bounds__(256) k_off(
    const _Float16* __restrict__ t2h,
    const _Float16* __restrict__ Wh,
    float* __restrict__ offp){
  __shared__ __align__(16) _Float16 sbuf[5120];
  int t = threadIdx.x;
  int w = t>>6, lane = t&63, col = lane&15, quad = lane>>4;
  int bid = blockIdx.x;
  int m0 = (bid/7)*64, n0 = (bid%7)*64;
  int r = t>>2;
  int arow = min(m0 + r, 391);
  int brow = min(n0 + r, 391);
  const _Float16* Bh = Wh + (size_t)5*WSZ;   // Wo2 (392x384)
  f4 acc[4] = {{0,0,0,0},{0,0,0,0},{0,0,0,0},{0,0,0,0}};
  gemm_fp16_body(t2h, Bh, arow, brow, sbuf, t, acc);
  #pragma unroll
  for (int nt = 0; nt < 4; ++nt){
    #pragma unroll
    for (int rr = 0; rr < 4; ++rr){
      int row = m0 + w*16 + quad*4 + rr;
      int o = n0 + nt*16 + col;
      if (row < 392 && o < 392){
        int g = o / NN, nn = o % NN;
        int b = row / SS, s = row % SS;
        float rng = (g == 0) ? (1.0f/HH) : (1.0f/WW);
        offp[((b*NN + nn)*SS + s)*2 + g] = tanhf(acc[nt][rr]) * rng * 2.0f;
      }
    }
  }
}

// ---------------- fused per-token: taps + softmax + agg scatter (no MFMA) ---
// launch_bounds(256,4): ~6 blocks/CU of work total -> deeper residency is
// useless; loosening to 4 lets the allocator use more VGPRs so P2's 24
// gathered loads stay in flight instead of serializing.
// agg LDS row stride = 228 (228%32=4 -> per-head bank offset 4h%32, worst 2-way)
__global__ void __launch_bounds__(256, 4) k_fused(
    const float* __restrict__ qf, const float* __restrict__ off,
    const _Float16* __restrict__ G16,
    const float* __restrict__ bk, const float* __restrict__ Wco, const float* __restrict__ pos,
    _Float16* __restrict__ agg16){
  __shared__ __align__(16) _Float16 Gs[2352];
  __shared__ __align__(16) float agg[12*228];    // front 384 aliases qrow
  __shared__ float scoreS[696];                  // [h*58+s]
  __shared__ float offl[98];
  __shared__ float colb[18];
  __shared__ float qbv[12];
  __shared__ uint2 tapv[232];                    // .x = weight f32 bits, .y = cell idx
  float* qrow = agg;

  int blk = blockIdx.x;
  int n = blk % NN, b = blk / NN;
  int iy = n / WW, ix = n % WW;
  int t = threadIdx.x;

  // ---- P0: vectorized loads ----
  {
    const h8* g8 = (const h8*)(G16 + (size_t)blk*2352);
    h8* gs8 = (h8*)Gs;
    for (int i = t; i < 294; i += 256) gs8[i] = g8[i];
  }
  {
    const f4* q4 = (const f4*)(qf + (size_t)blk*384);
    f4* qr4 = (f4*)qrow;
    for (int i = t; i < 96; i += 256) qr4[i] = q4[i];
  }
  for (int i = t; i < 98; i += 256) offl[i] = off[(size_t)blk*98 + i];
  __syncthreads();

  // ---- P1a: colb (co) and qbv[h] = q_h·bk_h ----
  if (t < 144){
    int o = t >> 3, l = t & 7;
    const float* wr = Wco + o*384 + l*48;
    const float* qr = qrow + l*48;
    f4 a4 = {0.f,0.f,0.f,0.f};
    #pragma unroll
    for (int c = 0; c < 48; c += 4) a4 += (*(const f4*)(qr + c)) * (*(const f4*)(wr + c));
    float acc = a4[0]+a4[1]+a4[2]+a4[3];
    acc += __shfl_xor(acc, 1); acc += __shfl_xor(acc, 2); acc += __shfl_xor(acc, 4);
    if (l == 0){
      int g = o & 1;
      float range = (g == 0) ? (1.0f/HH) : (1.0f/WW);
      colb[o] = tanhf(acc) * range;
    }
  }
  if (t >= 160){
    int o = t - 160;
    int h = o >> 3, l = o & 7;
    float acc = 0.f;
    for (int d = l; d < 32; d += 8) acc += qrow[h*32 + d] * bk[h*32 + d];
    acc += __shfl_xor(acc, 1); acc += __shfl_xor(acc, 2); acc += __shfl_xor(acc, 4);
    if (l == 0 && h < 12) qbv[h] = acc;
  }
  __syncthreads();

  // ---- P1b: taps (t<58) ----
  if (t < SK){
    float cy, cx;
    if (t < SS){
      int sy = t / RW, sx = t % RW;
      cy = offl[t*2+0] + ((2.0f*sy)/13.0f*2.0f - 1.0f);
      cx = offl[t*2+1] + ((2.0f*sx)/13.0f*2.0f - 1.0f);
    } else {
      int kk = t - SS;
      float cyr = fminf(fmaxf((float)iy + c_offm[kk][0], 0.f), (float)HH);
      float cxr = fminf(fmaxf((float)ix + c_offm[kk][1], 0.f), (float)WW);
      cy = colb[kk*2+0] + (cyr/13.0f*2.0f - 1.0f);
      cx = colb[kk*2+1] + (cxr/13.0f*2.0f - 1.0f);
    }
    float py = (cy + 1.0f)*0.5f*13.0f;
    float px = (cx + 1.0f)*0.5f*13.0f;
    float y0 = floorf(py), x0 = floorf(px);
    float wy1 = py - y0, wx1 = px - x0;
    #pragma unroll
    for (int k4 = 0; k4 < 4; ++k4){
      float yf = y0 + (k4 >> 1), xf = x0 + (k4 & 1);
      bool valid = (yf >= 0.f) && (yf <= 13.f) && (xf >= 0.f) && (xf <= 13.f);
      int yi = (int)fminf(fmaxf(yf, 0.f), 13.f);
      int xi = (int)fminf(fmaxf(xf, 0.f), 13.f);
      float wgt = ((k4 >> 1) ? wy1 : (1.f - wy1)) * ((k4 & 1) ? wx1 : (1.f - wx1));
      tapv[t*4 + k4] = make_uint2(__float_as_uint(valid ? wgt : 0.f),
                                  (unsigned)(yi*WW + xi));
    }
  }
  __syncthreads();   // taps + colb ready; now zero agg (qrow dead)
  for (int i = t; i < 12*228; i += 256) agg[i] = 0.f;

  // ---- P2 (s-major): 58 s x 4 groups of 3 heads; ALL loads hoisted ----
  if (t < 232){
    int s = t >> 2, grp = t & 3;
    float ry, rx;
    if (s < SS){
      int sy = s / RW, sx = s % RW;
      ry = (2.0f*sy - iy)/13.0f - offl[s*2+0];
      rx = (2.0f*sx - ix)/13.0f - offl[s*2+1];
    } else {
      int kk = s - SS;
      ry = colb[kk*2+0] - (float)iy;
      rx = colb[kk*2+1] - (float)ix;
    }
    float py = (ry + 1.0f)*0.5f*26.0f;
    float px = (rx + 1.0f)*0.5f*26.0f;
    float y0 = floorf(py), x0 = floorf(px);
    float wy1 = py - y0, wx1 = px - x0;
    int pidx[4]; float pw[4];
    #pragma unroll
    for (int k4 = 0; k4 < 4; ++k4){
      float yf = y0 + (k4 >> 1), xf = x0 + (k4 & 1);
      bool valid = (yf >= 0.f) && (yf <= 26.f) && (xf >= 0.f) && (xf <= 26.f);
      int yi = (int)fminf(fmaxf(yf, 0.f), 26.f);
      int xi = (int)fminf(fmaxf(xf, 0.f), 26.f);
      pidx[k4] = yi*TH + xi;
      float wgt = ((k4 >> 1) ? wy1 : (1.f - wy1)) * ((k4 & 1) ? wx1 : (1.f - wx1));
      pw[k4] = valid ? wgt : 0.f;
    }
    uint2 tp0 = tapv[s*4+0], tp1 = tapv[s*4+1], tp2 = tapv[s*4+2], tp3 = tapv[s*4+3];
    float tw0 = __uint_as_float(tp0.x), tw1 = __uint_as_float(tp1.x);
    float tw2 = __uint_as_float(tp2.x), tw3 = __uint_as_float(tp3.x);
    // hoist: issue all 12 global pos loads + 12 LDS G loads as independent ops
    float pv[3][4], gv[3][4];
    #pragma unroll
    for (int hh = 0; hh < 3; ++hh){
      const float* pt = pos + (grp*3 + hh)*729;
      pv[hh][0] = pt[pidx[0]]; pv[hh][1] = pt[pidx[1]];
      pv[hh][2] = pt[pidx[2]]; pv[hh][3] = pt[pidx[3]];
      const _Float16* gh = Gs + (grp*3 + hh)*196;
      gv[hh][0] = (float)gh[(int)tp0.y]; gv[hh][1] = (float)gh[(int)tp1.y];
      gv[hh][2] = (float)gh[(int)tp2.y]; gv[hh][3] = (float)gh[(int)tp3.y];
    }
    #pragma unroll
    for (int hh = 0; hh < 3; ++hh){
      int h = grp*3 + hh;
      float val = qbv[h];
      val += pv[hh][0]*pw[0];
      val += pv[hh][1]*pw[1];
      val += pv[hh][2]*pw[2];
      val += pv[hh][3]*pw[3];
      val += tw0*gv[hh][0];
      val += tw1*gv[hh][1];
      val += tw2*gv[hh][2];
      val += tw3*gv[hh][3];
      scoreS[h*58 + s] = val;
    }
  }
  __syncthreads();

  // ---- P3: softmax per head (192 threads) ----
  if (t < 192){
    int h = t >> 4, l = t & 15;
    float v[4];
    #pragma unroll
    for (int k = 0; k < 4; ++k){ int s = l + 16*k; v[k] = (s < SK) ? scoreS[h*58 + s] : -1e30f; }
    float mx = fmaxf(fmaxf(v[0], v[1]), fmaxf(v[2], v[3]));
    mx = fmaxf(mx, __shfl_xor(mx, 1)); mx = fmaxf(mx, __shfl_xor(mx, 2));
    mx = fmaxf(mx, __shfl_xor(mx, 4)); mx = fmaxf(mx, __shfl_xor(mx, 8));
    float e[4], sum = 0.f;
    #pragma unroll
    for (int k = 0; k < 4; ++k){ int s = l + 16*k; e[k] = (s < SK) ? expf(v[k] - mx) : 0.f; sum += e[k]; }
    sum += __shfl_xor(sum, 1); sum += __shfl_xor(sum, 2);
    sum += __shfl_xor(sum, 4); sum += __shfl_xor(sum, 8);
    float inv = 1.0f / sum;
    #pragma unroll
    for (int k = 0; k < 4; ++k){
      int s = l + 16*k;
      if (s < SK) scoreS[h*58 + s] = e[k]*inv;
    }
  }
  __syncthreads();

  // ---- P4 (tap-major): 232 threads, each scatters its tap into all 12 heads --
  if (t < 232){
    uint2 tp = tapv[t];
    float wv = __uint_as_float(tp.x);
    if (wv != 0.f){
      int s = t >> 2, cell = (int)tp.y;
      float* ag = agg + cell;
      #pragma unroll
      for (int h = 0; h < 12; ++h)
        atomicAdd(ag + h*228, scoreS[h*58 + s]*wv);
    }
  }
  __syncthreads();

  // ---- P5: vectorized write agg16 (dense 224-stride; pads are zero) ----
  {
    _Float16* ar = agg16 + (size_t)blk*2688;
    for (int i = t; i < 336; i += 256){
      int d = i*8;
      int h = d / 224, j = d - h*224;
      const float* src = agg + h*228 + j;
      f4 a = *(const f4*)src;
      f4 c = *(const f4*)(src + 4);
      h8 o;
      #pragma unroll
      for (int k = 0; k < 4; ++k){ o[k] = (_Float16)a[k]; o[4+k] = (_Float16)c[k]; }
      *(h8*)(ar + d) = o;
    }
  }
}

// -------- AV-GEMM -> otok fp16 --------
__global__ void __launch_bounds__(256) k_av(const _Float16* __restrict__ agg16,
                                            const _Float16* __restrict__ VprojT,
                                            const float* __restrict__ bv,
                                            _Float16* __restrict__ otokh){
  int t = threadIdx.x;
  int w = t>>6, lane = t&63, col = lane&15, quad = lane>>4;
  int m0 = blockIdx.x*64;
  int bh = blockIdx.y; int b = bh / 12, h = bh - b*12;
  const _Float16* ar = agg16 + ((size_t)(b*196 + min(m0 + w*16 + col, 195)))*2688 + h*224;
  f4 acc[2] = {{0,0,0,0},{0,0,0,0}};
  for (int kt = 0; kt < 7; ++kt){
    h8 a8 = *(const h8*)(ar + kt*32 + quad*8);
    #pragma unroll
    for (int nt = 0; nt < 2; ++nt){
      int o = h*32 + nt*16 + col;
      h8 b8 = *(const h8*)(VprojT + ((size_t)(b*384 + o))*224 + kt*32 + quad*8);
      acc[nt] = mfma16h(a8, b8, acc[nt]);
    }
  }
  #pragma unroll
  for (int nt = 0; nt < 2; ++nt){
    #pragma unroll
    for (int rr = 0; rr < 4; ++rr){
      int m = m0 + w*16 + quad*4 + rr;
      if (m < 196){
        int o = h*32 + nt*16 + col;
        float v = acc[nt][rr] + bv[o];
        otokh[((size_t)(b*196 + m))*384 + o] = (_Float16)v;
      }
    }
  }
}

// -------- final projection GEMM (fp16), transpose-scatter epilogue -----
__global__ void __launch_bounds__(256) k_proj(
    const _Float16* __restrict__ otokh,
    const _Float16* __restrict__ Wh,
    const float* __restrict__ bias, float* __restrict__ out){
  __shared__ __align__(16) _Float16 sbuf[5120];
  __shared__ float tile[16*65];
  int t = threadIdx.x;
  int w = t>>6, lane = t&63, col = lane&15, quad = lane>>4;
  int m0 = blockIdx.x*64, n0 = blockIdx.y*64;
  int r = t>>2;
  int arow = min(m0 + r, NTOK-1);
  int brow = n0 + r;
  const _Float16* Bh = Wh + (size_t)3*WSZ;   // Wp
  f4 acc[4] = {{0,0,0,0},{0,0,0,0},{0,0,0,0},{0,0,0,0}};
  gemm_fp16_body(otokh, Bh, arow, brow, sbuf, t, acc);
  // transpose-scatter in 4 passes of 16 m-rows through a 16x65 f32 tile
  #pragma unroll
  for (int pass = 0; pass < 4; ++pass){
    __syncthreads();
    if (w == pass){
      #pragma unroll
      for (int nt = 0; nt < 4; ++nt)
        #pragma unroll
        for (int rr = 0; rr < 4; ++rr)
          tile[(quad*4 + rr)*65 + nt*16 + col] = acc[nt][rr];
    }
    __syncthreads();
    for (int i = t; i < 256; i += 256){
      int o_l = i >> 2, ms = i & 3;
      int m = m0 + pass*16 + ms*4;
      if (m >= NTOK) continue;
      int bb = m / NN, nnn = m % NN;
      int o = n0 + o_l;
      float bo = bias[o];
      f4 v = { tile[(ms*4+0)*65 + o_l] + bo, tile[(ms*4+1)*65 + o_l] + bo,
               tile[(ms*4+2)*65 + o_l] + bo, tile[(ms*4+3)*65 + o_l] + bo };
      *(f4*)(out + ((size_t)bb*384 + o)*NN + nnn) = v;
    }
  }
}

extern "C" void kernel_launch(void* const* d_in, const int* in_sizes, int n_in,
                              void* d_out, int out_size, void* d_ws, size_t ws_size,
                              hipStream_t stream){
  const float* x    = (const float*)d_in[0];
  const float* Wq   = (const float*)d_in[1];
  const float* bq   = (const float*)d_in[2];
  const float* Wk   = (const float*)d_in[3];
  const float* bk   = (const float*)d_in[4];
  const float* Wv   = (const float*)d_in[5];
  const float* bv   = (const float*)d_in[6];
  const float* Wo1  = (const float*)d_in[7];
  const float* bo1  = (const float*)d_in[8];
  const float* Wdw  = (const float*)d_in[9];
  const float* bdw  = (const float*)d_in[10];
  const float* ln_g = (const float*)d_in[11];
  const float* ln_b = (const float*)d_in[12];
  const float* Wo2  = (const float*)d_in[13];
  const float* Wco  = (const float*)d_in[14];
  const float* pos  = (const float*)d_in[15];
  const float* Wp   = (const float*)d_in[16];
  const float* bp   = (const float*)d_in[17];
  float* out = (float*)d_out;

  float* ws   = (float*)d_ws;
  float* qf   = ws;                    // 602112 f32
  float* t1   = qf   + 602112;         // 602112 f32
  float* offp = t1   + 602112;         // 153664 f32
  _Float16* xhh    = (_Float16*)(offp + 153664);   // 602112 h
  _Float16* qfh    = xhh    + 602112;              // 602112 h
  _Float16* t2h    = qfh    + 602112;              // 150528 h
  _Float16* K2h    = t2h    + 150528;              // 602112 h
  _Float16* VprojT = K2h    + 602112;              // 688128 h
  _Float16* otokh  = VprojT + 688128;              // 602112 h
  _Float16* Wh     = otokh  + 602112;              // 5*147456 + 150528 h
  _Float16* G16    = Wh     + 5*WSZ + WO2SZ;       // 1568*2352 h
  _Float16* agg16  = G16    + 3687936;             // 1568*2688 h

  k_pre<<<498, 256, 0, stream>>>(x, xhh, Wq, Wk, Wo1, Wp, Wv, Wo2, Wh);
  k_qkv<<<492, 256, 0, stream>>>(xhh, Wh, bq, qf, qfh, K2h, VprojT);
  k_mid<<<534, 256, 0, stream>>>(qfh, Wh, bo1, t1, K2h, G16);
  k_dwln<<<392, 384, 0, stream>>>(t1, Wdw, bdw, ln_g, ln_b, t2h);
  k_off<<<49, 256, 0, stream>>>(t2h, Wh, offp);
  k_fused<<<1568, 256, 0, stream>>>(qf, offp, G16, bk, Wco, pos, agg16);
  k_av<<<dim3(4,96), 256, 0, stream>>>(agg16, VprojT, bv, otokh);
  k_proj<<<dim3(25,6), 256, 0, stream>>>(otokh, Wh, bp, out);
}